// Round 6
// baseline (125.221 us; speedup 1.0000x reference)
//
#include <hip/hip_runtime.h>

#define H 200
#define D 768
#define BATCH 4
#define S 512
#define M (BATCH*S)     // 2048
#define KP 224          // H padded to mult of 32 (MFMA K-step)
#define NCAT 400        // head|tail concatenated output cols
#define NC4 (H*H/4)     // 10000 float4-columns of V
#define VT_BLOCKS 313   // ceil(10000 cols / 32) ; block = 32 cols x 8 o-octs
#define PREP_BLOCKS 1000
#define LDSK 232        // LDS row stride (us) for hv tile: 464B, 16B-aligned,
                        // 116 dwords -> quad-dealiased banks

typedef __attribute__((ext_vector_type(8))) short bf16x8;   // 8 bf16 (4 VGPRs)
typedef __attribute__((ext_vector_type(4))) float f32x4;
typedef unsigned short us;

__device__ inline us f2bf(float f) {            // round-to-nearest-even fp32->bf16
    union { float f; unsigned u; } v; v.f = f;
    return (us)((v.u + 0x7FFF + ((v.u >> 16) & 1)) >> 16);
}

// ---------------------------------------------------------------------------
// prep: blocks [0,VT_BLOCKS): V = sum_o Wd[o]*U[o], 32 cols x 8 o-octs per
// block, LDS combine, transposed bf16 store into VTb[224,224].
// Remaining blocks grid-stride { x->bf16, W->bf16 transposed+concat, pads }.
// ---------------------------------------------------------------------------
__global__ __launch_bounds__(256) void prep(
        const float* __restrict__ x,  const float* __restrict__ Wh,
        const float* __restrict__ Wt, const float* __restrict__ U,
        const float* __restrict__ Wd,
        us* __restrict__ xb, us* __restrict__ Wcb, us* __restrict__ VTb,
        us* __restrict__ headb, us* __restrict__ tailb) {
    int bid = blockIdx.x;
    if (bid < VT_BLOCKS) {
        __shared__ float4 red[8][32];            // [oct][col] 4 KB
        int cl = threadIdx.x & 31, q = threadIdx.x >> 5;   // col-lane, o-oct
        int c = bid * 32 + cl;                   // float4-column of V
        const float4* U4 = (const float4*)U;
        float4 acc = make_float4(0.f, 0.f, 0.f, 0.f);
        if (c < NC4) {
            int o0 = q * 25;
            #pragma unroll
            for (int o = o0; o < o0 + 25; ++o) { // 25 independent 16B loads
                float w = Wd[o];
                float4 u = U4[(size_t)o * NC4 + c];
                acc.x += w * u.x; acc.y += w * u.y;
                acc.z += w * u.z; acc.w += w * u.w;
            }
        }
        red[q][cl] = acc;
        __syncthreads();
        if (q == 0 && c < NC4) {
            #pragma unroll
            for (int g = 1; g < 8; ++g) {
                float4 r = red[g][cl];
                acc.x += r.x; acc.y += r.y; acc.z += r.z; acc.w += r.w;
            }
            int i = c / (H / 4), j0 = (c % (H / 4)) * 4;  // V row i, cols j0..+3
            VTb[(j0 + 0) * KP + i] = f2bf(acc.x);         // VTb[n][k] = V[k][n]
            VTb[(j0 + 1) * KP + i] = f2bf(acc.y);
            VTb[(j0 + 2) * KP + i] = f2bf(acc.z);
            VTb[(j0 + 3) * KP + i] = f2bf(acc.w);
        }
        return;
    }
    const int GTH = (PREP_BLOCKS - VT_BLOCKS) * 256;
    int gtid = (bid - VT_BLOCKS) * 256 + threadIdx.x;
    // x -> bf16 (float4-vectorized; M*D/4 = 393216)
    {
        const float4* x4 = (const float4*)x;
        ushort4* xb4 = (ushort4*)xb;
        for (int t = gtid; t < M * D / 4; t += GTH) {
            float4 v = x4[t];
            ushort4 o; o.x = f2bf(v.x); o.y = f2bf(v.y); o.z = f2bf(v.z); o.w = f2bf(v.w);
            xb4[t] = o;
        }
    }
    // W transpose+concat -> bf16: Wcb[n*D+k] = W{h|t}[k][n]  (L2-resident rereads)
    for (int id = gtid; id < NCAT * D; id += GTH) {
        int n = id / D, k = id % D;
        float v = (n < H) ? Wh[k * H + n] : Wt[k * H + (n - H)];
        Wcb[id] = f2bf(v);
    }
    // pad zeroing (ws poisoned 0xAA every call)
    for (int id = gtid; id < M * (KP - H); id += GTH) {      // head/tail K-pad cols
        int r = id / (KP - H), c = H + id % (KP - H);
        headb[r * KP + c] = 0; tailb[r * KP + c] = 0;
    }
    for (int id = gtid; id < H * (KP - H); id += GTH) {      // VTb rows<H, k>=H
        int n = id / (KP - H), k = H + id % (KP - H);
        VTb[n * KP + k] = 0;
    }
    for (int id = gtid; id < (KP - H) * KP; id += GTH) {     // VTb rows [H,KP)
        int n = H + id / KP, k = id % KP;
        VTb[n * KP + k] = 0;
    }
}

// ---------------------------------------------------------------------------
// proj: C[2048,400] = xb[2048,768] @ Wcb^T; relu(+bias); split into headb|tailb
// One wave per 32x16 tile (verified round 2).
// ---------------------------------------------------------------------------
__global__ __launch_bounds__(64) void proj_mfma(
        const us* __restrict__ xb, const us* __restrict__ Wcb,
        const float* __restrict__ bh, const float* __restrict__ bt,
        us* __restrict__ headb, us* __restrict__ tailb) {
    int lane = threadIdx.x, quad = lane >> 4, col = lane & 15;
    int m0 = blockIdx.x * 32, n0 = blockIdx.y * 16;
    const bf16x8* A0 = (const bf16x8*)(xb + (m0 + col) * D + quad * 8);
    const bf16x8* A1 = (const bf16x8*)(xb + (m0 + 16 + col) * D + quad * 8);
    const bf16x8* Bp = (const bf16x8*)(Wcb + (n0 + col) * D + quad * 8);
    f32x4 acc0 = {0.f,0.f,0.f,0.f}, acc1 = {0.f,0.f,0.f,0.f};
    #pragma unroll 4
    for (int kk = 0; kk < D / 32; ++kk) {
        bf16x8 a0 = A0[kk * 4];
        bf16x8 a1 = A1[kk * 4];
        bf16x8 b  = Bp[kk * 4];
        acc0 = __builtin_amdgcn_mfma_f32_16x16x32_bf16(a0, b, acc0, 0, 0, 0);
        acc1 = __builtin_amdgcn_mfma_f32_16x16x32_bf16(a1, b, acc1, 0, 0, 0);
    }
    int n = n0 + col;
    bool ish = (n < H);
    float bias = ish ? bh[n] : bt[n - H];
    us* dst = ish ? headb : tailb;
    int nn = ish ? n : n - H;
    #pragma unroll
    for (int r = 0; r < 4; ++r) {
        int ma = m0 + quad * 4 + r;
        dst[ma * KP + nn]        = f2bf(fmaxf(acc0[r] + bias, 0.f));
        dst[(ma + 16) * KP + nn] = f2bf(fmaxf(acc1[r] + bias, 0.f));
    }
}

// ---------------------------------------------------------------------------
// Fused hv+scores. Block = (x-tile m0, y-half, batch b); 4 waves.
//  Phase A: waves cooperatively compute hv[m0..m0+31, 0..223] =
//           head-tile @ V^T (14 n-subtiles of 16), park bf16 in LDS in
//           A-fragment row-major layout (stride LDSK).
//  Phase B: each wave does 2 scores y-tiles (32x32): A from LDS, B = tail
//           from global, epilogue bias+scale to out.
// hv passes through bf16 exactly as the unfused version -> identical numerics.
// ---------------------------------------------------------------------------
__global__ __launch_bounds__(256) void hvscores(
        const us* __restrict__ headb, const us* __restrict__ VTb,
        const us* __restrict__ tailb, const float* __restrict__ bd,
        float* __restrict__ out) {
    __shared__ us hvs[32 * LDSK];                // 14.5 KB
    int w = threadIdx.x >> 6, lane = threadIdx.x & 63;
    int quad = lane >> 4, col = lane & 15;
    int b = blockIdx.z;
    int m0 = blockIdx.x * 32;
    const us* Ah = headb + (size_t)(b * S + m0) * KP;

    // ---- Phase A: hv tile -> LDS ----
    const bf16x8* A0 = (const bf16x8*)(Ah + col * KP + quad * 8);
    const bf16x8* A1 = (const bf16x8*)(Ah + (16 + col) * KP + quad * 8);
    for (int nt = w; nt < KP / 16; nt += 4) {    // 14 subtiles over 4 waves
        const bf16x8* Bp = (const bf16x8*)(VTb + (nt * 16 + col) * KP + quad * 8);
        f32x4 acc0 = {0.f,0.f,0.f,0.f}, acc1 = {0.f,0.f,0.f,0.f};
        #pragma unroll
        for (int kk = 0; kk < KP / 32; ++kk) {
            bf16x8 a0 = A0[kk * 4];
            bf16x8 a1 = A1[kk * 4];
            bf16x8 bf = Bp[kk * 4];
            acc0 = __builtin_amdgcn_mfma_f32_16x16x32_bf16(a0, bf, acc0, 0, 0, 0);
            acc1 = __builtin_amdgcn_mfma_f32_16x16x32_bf16(a1, bf, acc1, 0, 0, 0);
        }
        int n = nt * 16 + col;
        #pragma unroll
        for (int r = 0; r < 4; ++r) {            // C-layout: row quad*4+r, col n
            hvs[(quad * 4 + r) * LDSK + n]        = f2bf(acc0[r]);
            hvs[(16 + quad * 4 + r) * LDSK + n]   = f2bf(acc1[r]);
        }
    }
    __syncthreads();

    // ---- Phase B: scores y-tiles ----
    const us* Bt = tailb + (size_t)b * S * KP;
    const bf16x8* LA0 = (const bf16x8*)(hvs + col * LDSK + quad * 8);
    const bf16x8* LA1 = (const bf16x8*)(hvs + (16 + col) * LDSK + quad * 8);
    float bias = bd[0];
    const float scale = 0.07071067811865475f;    // 1/sqrt(200)
    float* outb = out + (size_t)b * S * S;
    for (int yi = 0; yi < 2; ++yi) {
        int yt = blockIdx.y * 8 + w + yi * 4;    // y-tile index 0..15
        int n0 = yt * 32;
        const bf16x8* B0 = (const bf16x8*)(Bt + (n0 + col) * KP + quad * 8);
        const bf16x8* B1 = (const bf16x8*)(Bt + (n0 + 16 + col) * KP + quad * 8);
        f32x4 a00 = {0.f,0.f,0.f,0.f}, a01 = {0.f,0.f,0.f,0.f};
        f32x4 a10 = {0.f,0.f,0.f,0.f}, a11 = {0.f,0.f,0.f,0.f};
        #pragma unroll
        for (int kk = 0; kk < KP / 32; ++kk) {
            bf16x8 a0 = LA0[kk * 4];             // LDS ds_read_b128, stride 29 dw
            bf16x8 a1 = LA1[kk * 4];
            bf16x8 b0 = B0[kk * 4];
            bf16x8 b1 = B1[kk * 4];
            a00 = __builtin_amdgcn_mfma_f32_16x16x32_bf16(a0, b0, a00, 0, 0, 0);
            a01 = __builtin_amdgcn_mfma_f32_16x16x32_bf16(a0, b1, a01, 0, 0, 0);
            a10 = __builtin_amdgcn_mfma_f32_16x16x32_bf16(a1, b0, a10, 0, 0, 0);
            a11 = __builtin_amdgcn_mfma_f32_16x16x32_bf16(a1, b1, a11, 0, 0, 0);
        }
        #pragma unroll
        for (int r = 0; r < 4; ++r) {
            int ma = m0 + quad * 4 + r, mb = ma + 16;
            outb[ma * S + n0 + col]      = (a00[r] + bias) * scale;
            outb[ma * S + n0 + 16 + col] = (a01[r] + bias) * scale;
            outb[mb * S + n0 + col]      = (a10[r] + bias) * scale;
            outb[mb * S + n0 + 16 + col] = (a11[r] + bias) * scale;
        }
    }
}

extern "C" void kernel_launch(void* const* d_in, const int* in_sizes, int n_in,
                              void* d_out, int out_size, void* d_ws, size_t ws_size,
                              hipStream_t stream) {
    const float* x  = (const float*)d_in[0];
    const float* Wh = (const float*)d_in[1];
    const float* bh = (const float*)d_in[2];
    const float* Wt = (const float*)d_in[3];
    const float* bt = (const float*)d_in[4];
    const float* U  = (const float*)d_in[5];
    const float* Wd = (const float*)d_in[6];
    const float* bd = (const float*)d_in[7];
    float* out = (float*)d_out;

    // ws layout (bf16): xb | Wcb | VTb[224*224] | headb | tailb  (~6.3 MB)
    us* xb    = (us*)d_ws;
    us* Wcb   = xb    + (size_t)M * D;
    us* VTb   = Wcb   + (size_t)NCAT * D;
    us* headb = VTb   + (size_t)KP * KP;
    us* tailb = headb + (size_t)M * KP;

    prep<<<PREP_BLOCKS, 256, 0, stream>>>(x, Wh, Wt, U, Wd,
                                          xb, Wcb, VTb, headb, tailb);
    proj_mfma<<<dim3(M / 32, NCAT / 16), 64, 0, stream>>>(xb, Wcb, bh, bt, headb, tailb);
    hvscores<<<dim3(S / 32, 2, BATCH), 256, 0, stream>>>(headb, VTb, tailb, bd, out);
}

// Round 7
// 117.142 us; speedup vs baseline: 1.0690x; 1.0690x over previous
//
#include <hip/hip_runtime.h>

#define H 200
#define D 768
#define BATCH 4
#define S 512
#define M (BATCH*S)     // 2048
#define KP 224          // H padded to mult of 32 (MFMA K-step)
#define NP 208          // H padded to mult of 16 (hv N-dim)
#define NCAT 400        // head|tail concatenated output cols
#define NC4 (H*H/4)     // 10000 float4-columns of V
#define VT_BLOCKS 625   // ceil(10000 cols / 16) ; block = 16 cols x 16 o-groups
#define PREP_BLOCKS 1000

typedef __attribute__((ext_vector_type(8))) short bf16x8;   // 8 bf16 (4 VGPRs)
typedef __attribute__((ext_vector_type(4))) float f32x4;
typedef unsigned short us;

__device__ inline us f2bf(float f) {            // round-to-nearest-even fp32->bf16
    union { float f; unsigned u; } v; v.f = f;
    return (us)((v.u + 0x7FFF + ((v.u >> 16) & 1)) >> 16);
}

// ---------------------------------------------------------------------------
// prep: blocks [0,VT_BLOCKS): V = sum_o Wd[o]*U[o] over 16 cols x 16 o-groups
// (12/13-deep chains, LDS combine, transposed bf16 store). Remaining 375
// blocks grid-stride { x->bf16, W->bf16 transposed+concat, pad zeroing }.
// ---------------------------------------------------------------------------
__global__ __launch_bounds__(256) void prep(
        const float* __restrict__ x,  const float* __restrict__ Wh,
        const float* __restrict__ Wt, const float* __restrict__ U,
        const float* __restrict__ Wd,
        us* __restrict__ xb, us* __restrict__ Wcb, us* __restrict__ VTb,
        us* __restrict__ headb, us* __restrict__ tailb, us* __restrict__ hvb) {
    int bid = blockIdx.x;
    if (bid < VT_BLOCKS) {
        __shared__ float4 red[16][16];           // [grp][col] 4 KB
        int cl = threadIdx.x & 15, q = threadIdx.x >> 4;   // col-lane, o-group
        int c = bid * 16 + cl;                   // float4-column of V
        const float4* U4 = (const float4*)U;
        float4 acc = make_float4(0.f, 0.f, 0.f, 0.f);
        if (c < NC4) {
            int o0  = q * 12 + min(q, 8);        // 8 groups of 13, 8 of 12
            int len = 12 + (q < 8 ? 1 : 0);
            for (int o = o0; o < o0 + len; ++o) {
                float w = Wd[o];
                float4 u = U4[(size_t)o * NC4 + c];  // quarter-wave 256B segments
                acc.x += w * u.x; acc.y += w * u.y;
                acc.z += w * u.z; acc.w += w * u.w;
            }
        }
        red[q][cl] = acc;
        __syncthreads();
        if (q == 0 && c < NC4) {
            #pragma unroll
            for (int g = 1; g < 16; ++g) {
                float4 r = red[g][cl];
                acc.x += r.x; acc.y += r.y; acc.z += r.z; acc.w += r.w;
            }
            int i = c / (H / 4), j0 = (c % (H / 4)) * 4;  // V row i, cols j0..+3
            VTb[(j0 + 0) * KP + i] = f2bf(acc.x);         // VTb[n][k] = V[k][n]
            VTb[(j0 + 1) * KP + i] = f2bf(acc.y);
            VTb[(j0 + 2) * KP + i] = f2bf(acc.z);
            VTb[(j0 + 3) * KP + i] = f2bf(acc.w);
        }
        return;
    }
    const int GTH = (PREP_BLOCKS - VT_BLOCKS) * 256;
    int gtid = (bid - VT_BLOCKS) * 256 + threadIdx.x;
    // x -> bf16 (float4-vectorized; M*D/4 = 393216)
    {
        const float4* x4 = (const float4*)x;
        ushort4* xb4 = (ushort4*)xb;
        for (int t = gtid; t < M * D / 4; t += GTH) {
            float4 v = x4[t];
            ushort4 o; o.x = f2bf(v.x); o.y = f2bf(v.y); o.z = f2bf(v.z); o.w = f2bf(v.w);
            xb4[t] = o;
        }
    }
    // W transpose+concat -> bf16: Wcb[n*D+k] = W{h|t}[k][n]  (L2-resident rereads)
    for (int id = gtid; id < NCAT * D; id += GTH) {
        int n = id / D, k = id % D;
        float v = (n < H) ? Wh[k * H + n] : Wt[k * H + (n - H)];
        Wcb[id] = f2bf(v);
    }
    // pad zeroing (ws poisoned 0xAA every call)
    for (int id = gtid; id < M * (KP - H); id += GTH) {      // head/tail K-pad
        int r = id / (KP - H), c = H + id % (KP - H);
        headb[r * KP + c] = 0; tailb[r * KP + c] = 0;
    }
    for (int id = gtid; id < M * (KP - NP); id += GTH) {     // hv K-pad
        int r = id / (KP - NP), c = NP + id % (KP - NP);
        hvb[r * KP + c] = 0;
    }
    for (int id = gtid; id < H * (KP - H); id += GTH) {      // VTb n<H, k>=H
        int n = id / (KP - H), k = H + id % (KP - H);
        VTb[n * KP + k] = 0;
    }
    for (int id = gtid; id < (NP - H) * KP; id += GTH) {     // VTb n in [H,NP)
        int n = H + id / KP, k = id % KP;
        VTb[n * KP + k] = 0;
    }
}

// ---------------------------------------------------------------------------
// proj: C[2048,400] = xb[2048,768] @ Wcb^T; relu(+bias); split into headb|tailb
// One wave per 32x16 tile (verified round 2).
// ---------------------------------------------------------------------------
__global__ __launch_bounds__(64) void proj_mfma(
        const us* __restrict__ xb, const us* __restrict__ Wcb,
        const float* __restrict__ bh, const float* __restrict__ bt,
        us* __restrict__ headb, us* __restrict__ tailb) {
    int lane = threadIdx.x, quad = lane >> 4, col = lane & 15;
    int m0 = blockIdx.x * 32, n0 = blockIdx.y * 16;
    const bf16x8* A0 = (const bf16x8*)(xb + (m0 + col) * D + quad * 8);
    const bf16x8* A1 = (const bf16x8*)(xb + (m0 + 16 + col) * D + quad * 8);
    const bf16x8* Bp = (const bf16x8*)(Wcb + (n0 + col) * D + quad * 8);
    f32x4 acc0 = {0.f,0.f,0.f,0.f}, acc1 = {0.f,0.f,0.f,0.f};
    #pragma unroll 4
    for (int kk = 0; kk < D / 32; ++kk) {
        bf16x8 a0 = A0[kk * 4];
        bf16x8 a1 = A1[kk * 4];
        bf16x8 b  = Bp[kk * 4];
        acc0 = __builtin_amdgcn_mfma_f32_16x16x32_bf16(a0, b, acc0, 0, 0, 0);
        acc1 = __builtin_amdgcn_mfma_f32_16x16x32_bf16(a1, b, acc1, 0, 0, 0);
    }
    int n = n0 + col;
    bool ish = (n < H);
    float bias = ish ? bh[n] : bt[n - H];
    us* dst = ish ? headb : tailb;
    int nn = ish ? n : n - H;
    #pragma unroll
    for (int r = 0; r < 4; ++r) {
        int ma = m0 + quad * 4 + r;
        dst[ma * KP + nn]        = f2bf(fmaxf(acc0[r] + bias, 0.f));
        dst[(ma + 16) * KP + nn] = f2bf(fmaxf(acc1[r] + bias, 0.f));
    }
}

// ---------------------------------------------------------------------------
// hv[2048,208] = headb[2048,224] @ VTb[208,224]^T
// ---------------------------------------------------------------------------
__global__ __launch_bounds__(64) void hv_mfma(
        const us* __restrict__ headb, const us* __restrict__ VTb,
        us* __restrict__ hvb) {
    int lane = threadIdx.x, quad = lane >> 4, col = lane & 15;
    int m0 = blockIdx.x * 32, n0 = blockIdx.y * 16;
    const bf16x8* A0 = (const bf16x8*)(headb + (m0 + col) * KP + quad * 8);
    const bf16x8* A1 = (const bf16x8*)(headb + (m0 + 16 + col) * KP + quad * 8);
    const bf16x8* Bp = (const bf16x8*)(VTb + (n0 + col) * KP + quad * 8);
    f32x4 acc0 = {0.f,0.f,0.f,0.f}, acc1 = {0.f,0.f,0.f,0.f};
    #pragma unroll
    for (int kk = 0; kk < KP / 32; ++kk) {
        bf16x8 a0 = A0[kk * 4];
        bf16x8 a1 = A1[kk * 4];
        bf16x8 b  = Bp[kk * 4];
        acc0 = __builtin_amdgcn_mfma_f32_16x16x32_bf16(a0, b, acc0, 0, 0, 0);
        acc1 = __builtin_amdgcn_mfma_f32_16x16x32_bf16(a1, b, acc1, 0, 0, 0);
    }
    int n = n0 + col;
    #pragma unroll
    for (int r = 0; r < 4; ++r) {
        int ma = m0 + quad * 4 + r;
        hvb[ma * KP + n]        = f2bf(acc0[r]);
        hvb[(ma + 16) * KP + n] = f2bf(acc1[r]);
    }
}

// ---------------------------------------------------------------------------
// scores[b,x,y] = (hv[b,x,:].tail[b,y,:] + b_down)/sqrt(200); 32x32 per wave
// ---------------------------------------------------------------------------
__global__ __launch_bounds__(64) void scores_mfma(
        const us* __restrict__ hvb, const us* __restrict__ tailb,
        const float* __restrict__ bd, float* __restrict__ out) {
    int lane = threadIdx.x, quad = lane >> 4, col = lane & 15;
    int b = blockIdx.z;
    int m0 = blockIdx.x * 32, n0 = blockIdx.y * 32;
    const us* A  = hvb   + (size_t)b * S * KP;
    const us* Bm = tailb + (size_t)b * S * KP;
    const bf16x8* A0 = (const bf16x8*)(A  + (m0 + col) * KP + quad * 8);
    const bf16x8* A1 = (const bf16x8*)(A  + (m0 + 16 + col) * KP + quad * 8);
    const bf16x8* B0 = (const bf16x8*)(Bm + (n0 + col) * KP + quad * 8);
    const bf16x8* B1 = (const bf16x8*)(Bm + (n0 + 16 + col) * KP + quad * 8);
    f32x4 a00 = {0.f,0.f,0.f,0.f}, a01 = {0.f,0.f,0.f,0.f};
    f32x4 a10 = {0.f,0.f,0.f,0.f}, a11 = {0.f,0.f,0.f,0.f};
    #pragma unroll
    for (int kk = 0; kk < KP / 32; ++kk) {
        bf16x8 a0 = A0[kk * 4];
        bf16x8 a1 = A1[kk * 4];
        bf16x8 b0 = B0[kk * 4];
        bf16x8 b1 = B1[kk * 4];
        a00 = __builtin_amdgcn_mfma_f32_16x16x32_bf16(a0, b0, a00, 0, 0, 0);
        a01 = __builtin_amdgcn_mfma_f32_16x16x32_bf16(a0, b1, a01, 0, 0, 0);
        a10 = __builtin_amdgcn_mfma_f32_16x16x32_bf16(a1, b0, a10, 0, 0, 0);
        a11 = __builtin_amdgcn_mfma_f32_16x16x32_bf16(a1, b1, a11, 0, 0, 0);
    }
    float bias = bd[0];
    const float scale = 0.07071067811865475f;   // 1/sqrt(200)
    float* outb = out + (size_t)b * S * S;
    #pragma unroll
    for (int r = 0; r < 4; ++r) {
        int ma = m0 + quad * 4 + r, mb = ma + 16;
        outb[ma * S + n0 + col]      = (a00[r] + bias) * scale;
        outb[ma * S + n0 + 16 + col] = (a01[r] + bias) * scale;
        outb[mb * S + n0 + col]      = (a10[r] + bias) * scale;
        outb[mb * S + n0 + 16 + col] = (a11[r] + bias) * scale;
    }
}

extern "C" void kernel_launch(void* const* d_in, const int* in_sizes, int n_in,
                              void* d_out, int out_size, void* d_ws, size_t ws_size,
                              hipStream_t stream) {
    const float* x  = (const float*)d_in[0];
    const float* Wh = (const float*)d_in[1];
    const float* bh = (const float*)d_in[2];
    const float* Wt = (const float*)d_in[3];
    const float* bt = (const float*)d_in[4];
    const float* U  = (const float*)d_in[5];
    const float* Wd = (const float*)d_in[6];
    const float* bd = (const float*)d_in[7];
    float* out = (float*)d_out;

    // ws layout (bf16): xb | Wcb | VTb | hvb | headb | tailb  (~6.6 MB)
    us* xb    = (us*)d_ws;
    us* Wcb   = xb    + (size_t)M * D;
    us* VTb   = Wcb   + (size_t)NCAT * D;
    us* hvb   = VTb   + (size_t)NP * KP;
    us* headb = hvb   + (size_t)M * KP;
    us* tailb = headb + (size_t)M * KP;

    prep<<<PREP_BLOCKS, 256, 0, stream>>>(x, Wh, Wt, U, Wd,
                                          xb, Wcb, VTb, headb, tailb, hvb);
    proj_mfma<<<dim3(M / 32, NCAT / 16), 64, 0, stream>>>(xb, Wcb, bh, bt, headb, tailb);
    hv_mfma<<<dim3(M / 32, NP / 16), 64, 0, stream>>>(headb, VTb, hvb);
    scores_mfma<<<dim3(S / 32, S / 32, BATCH), 64, 0, stream>>>(hvb, tailb, bd, out);
}